// Round 4
// baseline (1713.071 us; speedup 1.0000x reference)
//
#include <hip/hip_runtime.h>
#include <hip/hip_bf16.h>

#define D_DIM 1024
#define NTOK 267735
#define NEXT_ 267737   // + 2 cluster columns
#define HEADN 20000

typedef __attribute__((ext_vector_type(8))) short bf16x8;
typedef __attribute__((ext_vector_type(4))) float f32x4;

__device__ __forceinline__ int seg_of(int c){
  if (c < HEADN)  return 0;
  if (c < 20008)  return 1;
  if (c < 20016)  return 2;
  if (c < 200000) return 3;
  if (c < NTOK)   return 4;
  return 0; // cluster columns belong to head softmax
}

__device__ __forceinline__ unsigned pack2(float x, float y){
  __hip_bfloat16 a = __float2bfloat16(x);
  __hip_bfloat16 b = __float2bfloat16(y);
  unsigned short ua = *reinterpret_cast<unsigned short*>(&a);
  unsigned short ub = *reinterpret_cast<unsigned short*>(&b);
  return (unsigned)ua | ((unsigned)ub << 16);
}

#define BM 256
#define BN 128
#define BK 32
#define NTHREADS 512
#define KSTEPS (D_DIM/BK)   // 32

// LDS layout: [row][32] shorts (64B row). 16B chunk c of row r stored at
// chunk index c ^ ((r>>1)&3): writes conflict-free, b128 frag reads 2-way (free).
// Verified R2/R3: SQ_LDS_BANK_CONFLICT == 0.
__device__ __forceinline__ int swz_w(int r, int k4){   // short offset for 8B write
  int c = (k4 >> 1) ^ ((r >> 1) & 3);
  return r*32 + c*8 + (k4 & 1)*4;
}
__device__ __forceinline__ int swz_r(int row, int q){  // short offset for 16B read
  return row*32 + ((q ^ ((row >> 1) & 3)) << 3);
}

// Per-(row, segment) sum of exp(logit + bias) into accg[row*8 + seg].
// 2-phase double-buffered pipeline: loads for tile k+1 issued before the
// store+barrier+MFMA of tile k (T3-minimum + T14 issue-early/write-late).
__global__ __launch_bounds__(NTHREADS, 4) void gemm_lse_kernel(
    const float* __restrict__ hidden, const float* __restrict__ W,
    const float* __restrict__ bias,   const float* __restrict__ cw,
    const float* __restrict__ cb,     float* __restrict__ accg)
{
  __shared__ unsigned short lsA0[BM * 32];   // 16 KB
  __shared__ unsigned short lsB0[BN * 32];   //  8 KB
  __shared__ unsigned short lsA1[BM * 32];   // 16 KB
  __shared__ unsigned short lsB1[BN * 32];   //  8 KB

  const int tid = threadIdx.x;
  const int rowBase = blockIdx.x * BM;   // gridDim.x = 4 (adjacent -> L3 reuse of W strip)
  const int colBase = blockIdx.y * BN;

  // ---- staging assignments (8 lanes cover one row's 32-float k-slab) ----
  const float* aSrc[4]; int aRow[4], aK4[4];
#pragma unroll
  for (int i=0;i<4;++i){
    int idx = tid + NTHREADS*i;            // 0..2047 float4s of A tile
    aRow[i] = idx >> 3; aK4[i] = idx & 7;
    aSrc[i] = hidden + (size_t)(rowBase + aRow[i]) * D_DIM + aK4[i]*4;
  }
  const float* bSrc[2]; int bRow[2], bK4[2];
#pragma unroll
  for (int i=0;i<2;++i){
    int idx = tid + NTHREADS*i;            // 0..1023 float4s of B tile
    bRow[i] = idx >> 3; bK4[i] = idx & 7;
    int c = colBase + bRow[i];
    const float* base;
    if (c < NTOK)       base = W  + (size_t)c * D_DIM;
    else if (c < NEXT_) base = cw + (size_t)(c - NTOK) * D_DIM;
    else                base = W;          // dummy (masked in epilogue)
    bSrc[i] = base + bK4[i]*4;
  }

  const int lane = tid & 63;
  const int wv = tid >> 6;
  const int wm = wv >> 1;   // 0..3 : 64-row slab
  const int wn = wv & 1;    // 0..1 : 64-col slab
  const int q  = lane >> 4; // k-chunk
  const int r16 = lane & 15;

  f32x4 acc[4][4];
#pragma unroll
  for (int i=0;i<4;++i)
#pragma unroll
    for (int j=0;j<4;++j) acc[i][j] = (f32x4){0.f,0.f,0.f,0.f};

  float4 rA0[4], rB0[2], rA1[4], rB1[2];

  auto do_load_a = [&](float4* av, int kt){
#pragma unroll
    for (int i=0;i<4;++i) av[i] = *reinterpret_cast<const float4*>(aSrc[i] + kt*BK);
  };
  auto do_load_b = [&](float4* bv, int kt){
#pragma unroll
    for (int i=0;i<2;++i) bv[i] = *reinterpret_cast<const float4*>(bSrc[i] + kt*BK);
  };
  auto do_store = [&](unsigned short* LA, unsigned short* LB, const float4* av, const float4* bv){
#pragma unroll
    for (int i=0;i<4;++i){
      unsigned* p = reinterpret_cast<unsigned*>(&LA[swz_w(aRow[i], aK4[i])]);
      p[0] = pack2(av[i].x, av[i].y); p[1] = pack2(av[i].z, av[i].w);
    }
#pragma unroll
    for (int i=0;i<2;++i){
      unsigned* p = reinterpret_cast<unsigned*>(&LB[swz_w(bRow[i], bK4[i])]);
      p[0] = pack2(bv[i].x, bv[i].y); p[1] = pack2(bv[i].z, bv[i].w);
    }
  };
  auto do_mfma = [&](const unsigned short* LA, const unsigned short* LB){
    bf16x8 afr[4], bfr[4];
#pragma unroll
    for (int f=0; f<4; ++f) afr[f] = *reinterpret_cast<const bf16x8*>(&LA[swz_r(wm*64 + f*16 + r16, q)]);
#pragma unroll
    for (int f=0; f<4; ++f) bfr[f] = *reinterpret_cast<const bf16x8*>(&LB[swz_r(wn*64 + f*16 + r16, q)]);
#pragma unroll
    for (int i=0;i<4;++i)
#pragma unroll
      for (int j=0;j<4;++j)
        acc[i][j] = __builtin_amdgcn_mfma_f32_16x16x32_bf16(afr[i], bfr[j], acc[i][j], 0, 0, 0);
  };

  // prologue: tile 0 in flight
  do_load_a(rA0, 0); do_load_b(rB0, 0);

  for (int kt2 = 0; kt2 < KSTEPS/2; ++kt2){
    const int k0 = kt2*2;
    // ---- phase 0: compute tile k0 from buf0; prefetch tile k0+1 ----
    do_load_a(rA1, k0+1); do_load_b(rB1, k0+1);   // issue-early
    do_store(lsA0, lsB0, rA0, rB0);               // waits only on rA0/rB0 (counted vmcnt)
    __syncthreads();
    do_mfma(lsA0, lsB0);
    // ---- phase 1: compute tile k0+1 from buf1; prefetch tile k0+2 ----
    if (kt2 < KSTEPS/2 - 1){ do_load_a(rA0, k0+2); do_load_b(rB0, k0+2); }
    do_store(lsA1, lsB1, rA1, rB1);
    __syncthreads();
    do_mfma(lsA1, lsB1);
  }

  // ---- fused epilogue: exp + segmented reduce + atomic ----
  int sq[4]; float bq[4];
#pragma unroll
  for (int f=0; f<4; ++f){
    int c = colBase + wn*64 + f*16 + r16;
    if (c < NTOK)       { sq[f] = seg_of(c); bq[f] = bias[c]; }
    else if (c < NEXT_) { sq[f] = 0;         bq[f] = cb[c - NTOK]; }
    else                { sq[f] = -1;        bq[f] = 0.f; }
  }
  int sfirst = seg_of(colBase);
  int clast  = colBase + BN - 1; if (clast > NEXT_-1) clast = NEXT_-1;
  int slast  = seg_of(clast);
  int smin = sfirst, smax = slast;
  if (slast < sfirst){ smin = 0; smax = 4; }   // wrap tile at N_TOKEN boundary

#pragma unroll
  for (int i=0;i<4;++i){
#pragma unroll
    for (int r=0;r<4;++r){
      float e[4];
#pragma unroll
      for (int f=0;f<4;++f) e[f] = __expf(acc[i][f][r] + bq[f]);
      int rowg = rowBase + wm*64 + i*16 + (lane>>4)*4 + r;   // C/D: row=(l>>4)*4+reg
      for (int s = smin; s <= smax; ++s){
        float p = 0.f;
#pragma unroll
        for (int f=0;f<4;++f) p += (sq[f]==s) ? e[f] : 0.f;
#pragma unroll
        for (int off=1; off<16; off<<=1) p += __shfl_xor(p, off, 16);
        if ((lane & 15) == 0 && p != 0.f) atomicAdd(&accg[rowg*8 + s], p);
      }
    }
  }
}

// One wave per row: target logit + routing logit + final nll.
__global__ __launch_bounds__(256) void finalize_kernel(
    const float* __restrict__ hidden, const int* __restrict__ target,
    const float* __restrict__ W,      const float* __restrict__ bias,
    const float* __restrict__ cw,     const float* __restrict__ cb,
    const float* __restrict__ accg,   float* __restrict__ out)
{
  const int row  = blockIdx.x * 4 + (threadIdx.x >> 6);
  const int lane = threadIdx.x & 63;
  const int t = target[row];

  const float4* h4 = reinterpret_cast<const float4*>(hidden + (size_t)row * D_DIM);
  const float4* w1 = reinterpret_cast<const float4*>(W + (size_t)t * D_DIM);
  int s = 0; const float* jraw = W; float jb = 0.f;
  if (t >= HEADN){
    if      (t < 20008)  { s=1; jraw = W;          jb = bias[0]; }  // j = 0
    else if (t < 20016)  { s=2; jraw = W + D_DIM;  jb = bias[1]; }  // j = 1
    else if (t < 200000) { s=3; jraw = cw + D_DIM; jb = cb[1];   }  // j = 20001 -> cluster 1
    else                 { s=4; jraw = cw;         jb = cb[0];   }  // j = 20000 -> cluster 0
  }
  const float4* w2 = reinterpret_cast<const float4*>(jraw);

  float p1 = 0.f, p2 = 0.f;
#pragma unroll
  for (int j=0;j<4;++j){
    float4 hv = h4[lane + 64*j];
    float4 av = w1[lane + 64*j];
    float4 bv = w2[lane + 64*j];
    p1 += hv.x*av.x + hv.y*av.y + hv.z*av.z + hv.w*av.w;
    p2 += hv.x*bv.x + hv.y*bv.y + hv.z*bv.z + hv.w*bv.w;
  }
#pragma unroll
  for (int off=32; off; off>>=1){
    p1 += __shfl_xor(p1, off, 64);
    p2 += __shfl_xor(p2, off, 64);
  }

  if (lane == 0){
    float lseH = __logf(accg[row*8 + 0]);
    float nll;
    if (t < HEADN){
      nll = -(p1 + bias[t] - lseH);
    } else {
      float lseS = __logf(accg[row*8 + s]);
      nll = -((p2 + jb - lseH) + (p1 + bias[t] - lseS));
    }
    out[row] = nll;
  }
}

extern "C" void kernel_launch(void* const* d_in, const int* in_sizes, int n_in,
                              void* d_out, int out_size, void* d_ws, size_t ws_size,
                              hipStream_t stream)
{
  const float* hidden = (const float*)d_in[0];
  const int*   target = (const int*)  d_in[1];
  const float* W      = (const float*)d_in[2];
  const float* bias   = (const float*)d_in[3];
  const float* cw     = (const float*)d_in[4];
  const float* cb     = (const float*)d_in[5];
  float* out  = (float*)d_out;
  float* accg = (float*)d_ws;          // [1024][8] fp32 sum-of-exp accumulators

  hipMemsetAsync(accg, 0, 1024*8*sizeof(float), stream);

  dim3 grid(1024/BM, (NEXT_ + BN - 1)/BN);   // (4, 2092)
  gemm_lse_kernel<<<grid, NTHREADS, 0, stream>>>(hidden, W, bias, cw, cb, accg);
  finalize_kernel<<<256, 256, 0, stream>>>(hidden, target, W, bias, cw, cb, accg, out);
}

// Round 5
// 929.742 us; speedup vs baseline: 1.8425x; 1.8425x over previous
//
#include <hip/hip_runtime.h>
#include <hip/hip_bf16.h>

#define D_DIM 1024
#define NTOK 267735
#define NEXT_ 267737   // + 2 cluster columns
#define HEADN 20000

typedef __attribute__((ext_vector_type(8))) short bf16x8;
typedef __attribute__((ext_vector_type(4))) float f32x4;

__device__ __forceinline__ int seg_of(int c){
  if (c < HEADN)  return 0;
  if (c < 20008)  return 1;
  if (c < 20016)  return 2;
  if (c < 200000) return 3;
  if (c < NTOK)   return 4;
  return 0; // cluster columns belong to head softmax
}

__device__ __forceinline__ unsigned pack2(float x, float y){
  __hip_bfloat16 a = __float2bfloat16(x);
  __hip_bfloat16 b = __float2bfloat16(y);
  unsigned short ua = *reinterpret_cast<unsigned short*>(&a);
  unsigned short ub = *reinterpret_cast<unsigned short*>(&b);
  return (unsigned)ua | ((unsigned)ub << 16);
}

#define BM 256
#define BN 128
#define BK 32
#define NTHREADS 512
#define NCOLT 2092          // ceil(NEXT_/BN)
#define NBLK 8384           // 8 XCD * 1048 (padded; 16 dead blocks return early)

// LDS layout: [row][32] shorts (64B row). 16B chunk c of row r stored at
// chunk index c ^ ((r>>1)&3): writes conflict-free, b128 frag reads 2-way (free).
// Verified R2/R3: SQ_LDS_BANK_CONFLICT == 0.
__device__ __forceinline__ int swz_w(int r, int k4){   // short offset for 8B write
  int c = (k4 >> 1) ^ ((r >> 1) & 3);
  return r*32 + c*8 + (k4 & 1)*4;
}
__device__ __forceinline__ int swz_r(int row, int q){  // short offset for 16B read
  return row*32 + ((q ^ ((row >> 1) & 3)) << 3);
}

// Computes per-(row, segment) sum of exp(logit + bias) into accg[row*8 + seg].
// XCD-aware remap: the 4 row-blocks sharing one 128-col W strip (512 KB) get
// linear bids {b0, b0+8, b0+16, b0+24} -> same XCD under round-robin dispatch
// -> W strip fetched from HBM once, served from that XCD's L2 to the other 3.
__global__ __launch_bounds__(NTHREADS, 1) void gemm_lse_kernel(
    const float* __restrict__ hidden, const float* __restrict__ W,
    const float* __restrict__ bias,   const float* __restrict__ cw,
    const float* __restrict__ cb,     float* __restrict__ accg)
{
  const int b = blockIdx.x;
  const int k8 = b & 7;          // XCD slot
  const int s  = b >> 3;         // sequence within XCD
  const int xb = s & 3;          // row-block 0..3
  const int yb = (s >> 2) * 8 + k8;  // col-strip
  if (yb >= NCOLT) return;       // 16 pad blocks

  __shared__ unsigned short lsA[BM * 32];   // 16 KB
  __shared__ unsigned short lsB[BN * 32];   //  8 KB

  const int tid = threadIdx.x;
  const int rowBase = xb * BM;
  const int colBase = yb * BN;

  // ---- staging assignments (coalesced: 8 lanes cover one row's 32-float k-slab) ----
  const float* aSrc[4]; int aRow[4], aK4[4];
#pragma unroll
  for (int i=0;i<4;++i){
    int idx = tid + NTHREADS*i;            // 0..2047 float4s of A tile
    aRow[i] = idx >> 3; aK4[i] = idx & 7;
    aSrc[i] = hidden + (size_t)(rowBase + aRow[i]) * D_DIM + aK4[i]*4;
  }
  const float* bSrc[2]; int bRow[2], bK4[2];
#pragma unroll
  for (int i=0;i<2;++i){
    int idx = tid + NTHREADS*i;            // 0..1023 float4s of B tile
    bRow[i] = idx >> 3; bK4[i] = idx & 7;
    int c = colBase + bRow[i];
    const float* base;
    if (c < NTOK)       base = W  + (size_t)c * D_DIM;
    else if (c < NEXT_) base = cw + (size_t)(c - NTOK) * D_DIM;
    else                base = W;          // dummy (masked in epilogue)
    bSrc[i] = base + bK4[i]*4;
  }

  const int lane = tid & 63;
  const int wv = tid >> 6;
  const int wm = wv >> 1;   // 0..3 : 64-row slab
  const int wn = wv & 1;    // 0..1 : 64-col slab
  const int q  = lane >> 4; // k-chunk
  const int r16 = lane & 15;

  f32x4 acc[4][4];
#pragma unroll
  for (int i=0;i<4;++i)
#pragma unroll
    for (int j=0;j<4;++j) acc[i][j] = (f32x4){0.f,0.f,0.f,0.f};

  for (int kt = 0; kt < D_DIM/BK; ++kt){
    float4 av[4], bv[2];
#pragma unroll
    for (int i=0;i<4;++i) av[i] = *reinterpret_cast<const float4*>(aSrc[i] + kt*BK);
#pragma unroll
    for (int i=0;i<2;++i) bv[i] = *reinterpret_cast<const float4*>(bSrc[i] + kt*BK);
    __syncthreads();   // previous iteration's reads done
#pragma unroll
    for (int i=0;i<4;++i){
      unsigned* p = reinterpret_cast<unsigned*>(&lsA[swz_w(aRow[i], aK4[i])]);
      p[0] = pack2(av[i].x, av[i].y); p[1] = pack2(av[i].z, av[i].w);
    }
#pragma unroll
    for (int i=0;i<2;++i){
      unsigned* p = reinterpret_cast<unsigned*>(&lsB[swz_w(bRow[i], bK4[i])]);
      p[0] = pack2(bv[i].x, bv[i].y); p[1] = pack2(bv[i].z, bv[i].w);
    }
    __syncthreads();
    bf16x8 afr[4], bfr[4];
#pragma unroll
    for (int f=0; f<4; ++f) afr[f] = *reinterpret_cast<const bf16x8*>(&lsA[swz_r(wm*64 + f*16 + r16, q)]);
#pragma unroll
    for (int f=0; f<4; ++f) bfr[f] = *reinterpret_cast<const bf16x8*>(&lsB[swz_r(wn*64 + f*16 + r16, q)]);
#pragma unroll
    for (int i=0;i<4;++i)
#pragma unroll
      for (int j=0;j<4;++j)
        acc[i][j] = __builtin_amdgcn_mfma_f32_16x16x32_bf16(afr[i], bfr[j], acc[i][j], 0, 0, 0);
  }

  // ---- fused epilogue: exp + segmented reduce + atomic ----
  int sq[4]; float bq[4];
#pragma unroll
  for (int f=0; f<4; ++f){
    int c = colBase + wn*64 + f*16 + r16;
    if (c < NTOK)       { sq[f] = seg_of(c); bq[f] = bias[c]; }
    else if (c < NEXT_) { sq[f] = 0;         bq[f] = cb[c - NTOK]; }
    else                { sq[f] = -1;        bq[f] = 0.f; }
  }
  int sfirst = seg_of(colBase);
  int clast  = colBase + BN - 1; if (clast > NEXT_-1) clast = NEXT_-1;
  int slast  = seg_of(clast);
  int smin = sfirst, smax = slast;
  if (slast < sfirst){ smin = 0; smax = 4; }   // wrap tile at N_TOKEN boundary

#pragma unroll
  for (int i=0;i<4;++i){
#pragma unroll
    for (int r=0;r<4;++r){
      float e[4];
#pragma unroll
      for (int f=0;f<4;++f) e[f] = __expf(acc[i][f][r] + bq[f]);
      int rowg = rowBase + wm*64 + i*16 + (lane>>4)*4 + r;   // C/D: row=(l>>4)*4+reg
      for (int s2 = smin; s2 <= smax; ++s2){
        float p = 0.f;
#pragma unroll
        for (int f=0;f<4;++f) p += (sq[f]==s2) ? e[f] : 0.f;
#pragma unroll
        for (int off=1; off<16; off<<=1) p += __shfl_xor(p, off, 16);
        if ((lane & 15) == 0 && p != 0.f) atomicAdd(&accg[rowg*8 + s2], p);
      }
    }
  }
}

// One wave per row: target logit + routing logit + final nll.
__global__ __launch_bounds__(256) void finalize_kernel(
    const float* __restrict__ hidden, const int* __restrict__ target,
    const float* __restrict__ W,      const float* __restrict__ bias,
    const float* __restrict__ cw,     const float* __restrict__ cb,
    const float* __restrict__ accg,   float* __restrict__ out)
{
  const int row  = blockIdx.x * 4 + (threadIdx.x >> 6);
  const int lane = threadIdx.x & 63;
  const int t = target[row];

  const float4* h4 = reinterpret_cast<const float4*>(hidden + (size_t)row * D_DIM);
  const float4* w1 = reinterpret_cast<const float4*>(W + (size_t)t * D_DIM);
  int s = 0; const float* jraw = W; float jb = 0.f;
  if (t >= HEADN){
    if      (t < 20008)  { s=1; jraw = W;          jb = bias[0]; }  // j = 0
    else if (t < 20016)  { s=2; jraw = W + D_DIM;  jb = bias[1]; }  // j = 1
    else if (t < 200000) { s=3; jraw = cw + D_DIM; jb = cb[1];   }  // j = 20001 -> cluster 1
    else                 { s=4; jraw = cw;         jb = cb[0];   }  // j = 20000 -> cluster 0
  }
  const float4* w2 = reinterpret_cast<const float4*>(jraw);

  float p1 = 0.f, p2 = 0.f;
#pragma unroll
  for (int j=0;j<4;++j){
    float4 hv = h4[lane + 64*j];
    float4 av = w1[lane + 64*j];
    float4 bv = w2[lane + 64*j];
    p1 += hv.x*av.x + hv.y*av.y + hv.z*av.z + hv.w*av.w;
    p2 += hv.x*bv.x + hv.y*bv.y + hv.z*bv.z + hv.w*bv.w;
  }
#pragma unroll
  for (int off=32; off; off>>=1){
    p1 += __shfl_xor(p1, off, 64);
    p2 += __shfl_xor(p2, off, 64);
  }

  if (lane == 0){
    float lseH = __logf(accg[row*8 + 0]);
    float nll;
    if (t < HEADN){
      nll = -(p1 + bias[t] - lseH);
    } else {
      float lseS = __logf(accg[row*8 + s]);
      nll = -((p2 + jb - lseH) + (p1 + bias[t] - lseS));
    }
    out[row] = nll;
  }
}

extern "C" void kernel_launch(void* const* d_in, const int* in_sizes, int n_in,
                              void* d_out, int out_size, void* d_ws, size_t ws_size,
                              hipStream_t stream)
{
  const float* hidden = (const float*)d_in[0];
  const int*   target = (const int*)  d_in[1];
  const float* W      = (const float*)d_in[2];
  const float* bias   = (const float*)d_in[3];
  const float* cw     = (const float*)d_in[4];
  const float* cb     = (const float*)d_in[5];
  float* out  = (float*)d_out;
  float* accg = (float*)d_ws;          // [1024][8] fp32 sum-of-exp accumulators

  hipMemsetAsync(accg, 0, 1024*8*sizeof(float), stream);

  gemm_lse_kernel<<<NBLK, NTHREADS, 0, stream>>>(hidden, W, bias, cw, cb, accg);
  finalize_kernel<<<256, 256, 0, stream>>>(hidden, target, W, bias, cw, cb, accg, out);
}